// Round 8
// baseline (652.204 us; speedup 1.0000x reference)
//
#include <hip/hip_runtime.h>
#include <hip/hip_bf16.h>
#include <stdint.h>

// Problem constants (fixed by the reference)
#define NN   50000
#define RR   50
#define BB   30
#define DIN  64
#define EE   1000000
#define KTOT (BB*DIN + DIN)   // 1984
#define NBW  16               // nodes per workgroup; 50000 = 3125*16 exactly
#define TROW 2000             // t_tile row stride in shorts (16B-aligned rows, odd/8 dword stride)

typedef __attribute__((ext_vector_type(8)))  short short8;
typedef __attribute__((ext_vector_type(4)))  float floatx4;
typedef __attribute__((ext_vector_type(16))) float floatx16;

#define RFL(x) __builtin_amdgcn_readfirstlane(x)

__device__ __forceinline__ int imin(int a, int b) { return a < b ? a : b; }

// async 16B/lane global->LDS: dest = (wave-uniform) lds base + lane*16
__device__ __forceinline__ void async16(const void* g, void* l) {
    __builtin_amdgcn_global_load_lds(
        (const __attribute__((address_space(1))) unsigned int*)g,
        (__attribute__((address_space(3))) unsigned int*)l, 16, 0, 0);
}

// ---------------- preprocessing: counting sort of edges by dst ----------------

__global__ void k_hist(const int* __restrict__ dst, const int* __restrict__ et,
                       int* __restrict__ cnt, int* __restrict__ dcount) {
    int e = blockIdx.x * 256 + threadIdx.x;
    if (e < EE) {
        int d = dst[e], r = et[e];
        atomicAdd(&cnt[d * RR + r], 1);
        atomicAdd(&dcount[d], 1);
    }
}

__global__ void k_scan1(const int* __restrict__ dcount, int* __restrict__ doff,
                        int* __restrict__ bsum) {
    __shared__ int sh[256];
    int t = threadIdx.x;
    int i = blockIdx.x * 256 + t;
    int v = (i < NN) ? dcount[i] : 0;
    sh[t] = v;
    __syncthreads();
    for (int s = 1; s < 256; s <<= 1) {
        int add = (t >= s) ? sh[t - s] : 0;
        __syncthreads();
        sh[t] += add;
        __syncthreads();
    }
    int incl = sh[t];
    if (i < NN) doff[i] = incl - v;
    if (t == 255) bsum[blockIdx.x] = incl;
}

__global__ void k_scan2(int* __restrict__ bsum, int nbv) {
    __shared__ int sh[256];
    int t = threadIdx.x;
    int v = (t < nbv) ? bsum[t] : 0;
    sh[t] = v;
    __syncthreads();
    for (int s = 1; s < 256; s <<= 1) {
        int add = (t >= s) ? sh[t - s] : 0;
        __syncthreads();
        sh[t] += add;
        __syncthreads();
    }
    if (t < nbv) bsum[t] = sh[t] - v;
}

__global__ void k_scan3(int* __restrict__ doff, const int* __restrict__ bsum) {
    int i = blockIdx.x * 256 + threadIdx.x;
    if (i < NN) doff[i] += bsum[blockIdx.x];
}

__global__ void k_scatter(const int* __restrict__ src, const int* __restrict__ dst,
                          const int* __restrict__ et, const int* __restrict__ cnt,
                          const int* __restrict__ doff, int* __restrict__ cursor,
                          int4* __restrict__ epack) {
    int e = blockIdx.x * 256 + threadIdx.x;
    if (e < EE) {
        int d = dst[e], r = et[e], s = src[e];
        int p = doff[d] + atomicAdd(&cursor[d], 1);
        float a = 1.0f / (float)cnt[d * RR + r];
        epack[p] = make_int4(s, r, __float_as_int(a), 0);
    }
}

__global__ void k_cast_x(const float* __restrict__ x, __hip_bfloat16* __restrict__ h) {
    int i = blockIdx.x * 256 + threadIdx.x;
    if (i < NN * DIN) h[i] = __float2bfloat16(x[i]);
}

// all 3 layers' comp [R,30] fp32 -> bf16 padded [3][R][32] (zeros in 30,31)
__global__ void k_prep_cb3(const float* __restrict__ c0, const float* __restrict__ c1,
                           const float* __restrict__ c2, short* __restrict__ cb) {
    int idx = blockIdx.x * 256 + threadIdx.x;
    if (idx < 3 * RR * 32) {
        int l = idx / (RR * 32);
        int rem = idx - l * (RR * 32);
        int r = rem >> 5, i = rem & 31;
        const float* c = (l == 0) ? c0 : (l == 1) ? c1 : c2;
        float v = (i < BB) ? c[r * BB + i] : 0.f;
        __hip_bfloat16 hb = __float2bfloat16(v);
        cb[idx] = *reinterpret_cast<const short*>(&hb);
    }
}

// all 3 layers' transposed bf16 weights:
// rows [0,64): layer0; [64,128): layer1; [128,144): layer2 (dout=8, 16 padded rows)
__global__ void k_prep_w3(const float* __restrict__ b0, const float* __restrict__ r0,
                          const float* __restrict__ b1, const float* __restrict__ r1,
                          const float* __restrict__ b2, const float* __restrict__ r2,
                          short* __restrict__ wt) {
    int idx = blockIdx.x * 256 + threadIdx.x;
    if (idx >= 144 * KTOT) return;
    int row = idx / KTOT, k = idx - row * KTOT;
    const float* bs; const float* rt; int o, dout;
    if (row < 64)       { bs = b0; rt = r0; o = row;        dout = 64; }
    else if (row < 128) { bs = b1; rt = r1; o = row - 64;   dout = 64; }
    else                { bs = b2; rt = r2; o = row - 128;  dout = 8;  }
    float v = 0.f;
    if (o < dout)
        v = (k < BB * DIN) ? bs[k * dout + o] : rt[(k - BB * DIN) * dout + o];
    __hip_bfloat16 hb = __float2bfloat16(v);
    wt[idx] = *reinterpret_cast<const short*>(&hb);
}

// ---------------- fused per-layer kernel ----------------
// 1024 threads = 16 waves. Phase 1 (MFMA aggregation): wave wv owns node wv.
//   Per 16-edge chunk: x rows staged to LDS via global_load_lds (per-lane gather
//   addresses); A = comp[rel_k][b]*alpha_k built from L1-resident bf16 comp table
//   + scalar-loaded records; two v_mfma_f32_32x32x16_bf16 accumulate t(32x64).
//   Padded edges get alpha=0 (garbage B rows contribute 0).
// Barrier, C/D regs -> t_tile bf16 (aliases the staging area), barrier.
// Phase 2: 16 waves; each reads one A-frag per K-step and feeds 2 col-tiles
//   (DOUT=64: 2 colpairs x 8 K-parts; DOUT=8: 16 K-parts). Partials reduced
//   through LDS (t_tile space, after barrier).
template <int DOUT, bool RELU>
__global__ __launch_bounds__(1024, 4)
void k_fused(const __hip_bfloat16* __restrict__ xin,
             const int4* __restrict__ epack,
             const int* __restrict__ doff, const int* __restrict__ dcount,
             const short* __restrict__ cpb,     // [R][32] bf16 (this layer)
             const short* __restrict__ Wt,      // [DPAD][KTOT] bf16 (transposed)
             const float* __restrict__ bias,    // [DOUT]
             void* __restrict__ outp) {
    __shared__ __align__(16) char smem[NBW * TROW * 2];   // 64000 B; stage aliases front 32KB
    short* t_tile = (short*)smem;

    const int tid  = threadIdx.x;
    const int lane = tid & 63;
    const int wv   = RFL(tid >> 6);          // 0..15
    const int node0 = blockIdx.x * NBW;
    const int m    = lane & 31;
    const bool hi  = (lane >= 32);

    // ---- phase 1: one node per wave, MFMA over 16-edge chunks ----
    floatx16 acc0 = {0.f,0.f,0.f,0.f,0.f,0.f,0.f,0.f,0.f,0.f,0.f,0.f,0.f,0.f,0.f,0.f};
    floatx16 acc1 = acc0;
    {
        const int n = node0 + wv;
        const int beg = RFL(doff[n]), cnt = RFL(dcount[n]);
        const int nch = (cnt + 15) >> 4;
        char*  sst_b = smem + wv * 2048;            // this wave's 2KB staging slot
        const short* sst = (const short*)sst_b;
        const int eg  = lane >> 3;                  // edge-in-group 0..7
        const int sub = (lane & 7) * 16;            // byte offset within x row
        const int k0  = (lane >> 5) * 8;            // frag k-base

        int4 vr0, vr1;
        if (nch > 0) {
            vr0 = epack[imin(beg + eg,     EE - 1)];
            vr1 = epack[imin(beg + eg + 8, EE - 1)];
        }
        for (int c = 0; c < nch; ++c) {
            const int cb = beg + c * 16;
            // stage chunk c (vr prefetched)
            const char* g0 = (const char*)xin + ((size_t)(unsigned)vr0.x) * 128 + sub;
            const char* g1 = (const char*)xin + ((size_t)(unsigned)vr1.x) * 128 + sub;
            async16(g0, sst_b);
            async16(g1, sst_b + 1024);
            // prefetch next chunk's staging records
            if (c + 1 < nch) {
                const int nb = cb + 16;
                vr0 = epack[imin(nb + eg,     EE - 1)];
                vr1 = epack[imin(nb + eg + 8, EE - 1)];
            }
            // scalar records for A side (uniform addresses -> s_load)
            int relA[8], relB[8]; float alA[8], alB[8];
#pragma unroll
            for (int t = 0; t < 8; ++t) {
                int4 ea = epack[imin(cb + t,     EE - 1)];
                int4 eb = epack[imin(cb + 8 + t, EE - 1)];
                relA[t] = ea.y;
                relB[t] = eb.y;
                alA[t] = (c * 16 + t     < cnt) ? __int_as_float(ea.z) : 0.f;
                alB[t] = (c * 16 + 8 + t < cnt) ? __int_as_float(eb.z) : 0.f;
            }
            // A-frag: af[t] = bf16( comp[rel_{k0+t}][m] * alpha_{k0+t} )
            short8 af;
#pragma unroll
            for (int t = 0; t < 8; ++t) {
                int   rel = hi ? relB[t] : relA[t];
                float al  = hi ? alB[t]  : alA[t];
                unsigned short cv = ((const unsigned short*)cpb)[rel * 32 + m];
                float cf = __int_as_float(((int)cv) << 16);
                af[t] = (short)(((unsigned)__float_as_int(cf * al)) >> 16);
            }
            // wait staged x (and comp gathers) landed
            __builtin_amdgcn_s_waitcnt(0x0F70);   // vmcnt(0)
            __builtin_amdgcn_sched_barrier(0);
            // B-frags: bf[t] = x_stage[k0+t][n], n = m (+32)
            short8 bf0, bf1;
#pragma unroll
            for (int t = 0; t < 8; ++t) {
                bf0[t] = sst[(k0 + t) * 64 + m];
                bf1[t] = sst[(k0 + t) * 64 + 32 + m];
            }
            acc0 = __builtin_amdgcn_mfma_f32_32x32x16_bf16(af, bf0, acc0, 0, 0, 0);
            acc1 = __builtin_amdgcn_mfma_f32_32x32x16_bf16(af, bf1, acc1, 0, 0, 0);
        }
    }
    __syncthreads();   // all staging reads done; safe to overwrite with t_tile

    // C/D -> t_tile (bf16). layout: col=lane&31, row=(reg&3)+8*(reg>>2)+4*(lane>>5)
    {
        short* trow = t_tile + wv * TROW;
#pragma unroll
        for (int r = 0; r < 16; ++r) {
            const int b = (r & 3) + 8 * (r >> 2) + 4 * (lane >> 5);
            if (b < BB) {
                __hip_bfloat16 h0 = __float2bfloat16(acc0[r]);
                __hip_bfloat16 h1 = __float2bfloat16(acc1[r]);
                trow[b * 64 + m]      = *reinterpret_cast<const short*>(&h0);
                trow[b * 64 + 32 + m] = *reinterpret_cast<const short*>(&h1);
            }
        }
        // self/root term: raw bf16 copy of x[n]
        trow[BB * 64 + lane] = ((const short*)xin)[(node0 + wv) * 64 + lane];
    }
    __syncthreads();

    // ---- phase 2: out = t(16xK) * Wt^T, MFMA 16x16x32, K = 1984 (62 steps) ----
    const int mm = lane & 15;
    const int qq = lane >> 4;
    floatx4 p0 = {0.f, 0.f, 0.f, 0.f};
    floatx4 p1 = {0.f, 0.f, 0.f, 0.f};
    int cp, kp;
    if (DOUT == 64) { cp = wv & 1; kp = wv >> 1; }
    else            { cp = 0;      kp = wv;      }
    int kk0, nst;
    if (DOUT == 64) { kk0 = (kp < 6)  ? kp * 8 : 48 + (kp - 6)  * 7; nst = (kp < 6)  ? 8 : 7; }
    else            { kk0 = (kp < 14) ? kp * 4 : 56 + (kp - 14) * 3; nst = (kp < 14) ? 4 : 3; }

    {
        const short* arow = t_tile + mm * TROW + qq * 8;
        const short* b0row = Wt + (size_t)(cp * 32 + mm) * KTOT + qq * 8;
        const short* b1row = Wt + (size_t)(cp * 32 + 16 + mm) * KTOT + qq * 8;
        for (int s = 0; s < nst; ++s) {
            const int kk = kk0 + s;
            short8 a  = *reinterpret_cast<const short8*>(arow + kk * 32);
            short8 w0 = *reinterpret_cast<const short8*>(b0row + kk * 32);
            p0 = __builtin_amdgcn_mfma_f32_16x16x32_bf16(a, w0, p0, 0, 0, 0);
            if (DOUT == 64) {
                short8 w1 = *reinterpret_cast<const short8*>(b1row + kk * 32);
                p1 = __builtin_amdgcn_mfma_f32_16x16x32_bf16(a, w1, p1, 0, 0, 0);
            }
        }
    }

    __syncthreads();                  // t_tile reads done -> reuse as reduction buffer
    float* red = (float*)smem;

    if (DOUT == 64) {
        // 8 K-parts per colpair; parts 1..7 write (stride-9 floats), part 0 reduces
        if (kp > 0) {
            const int off = ((cp * 7 + (kp - 1)) * 64 + lane) * 9;
#pragma unroll
            for (int i = 0; i < 4; ++i) { red[off + i] = p0[i]; red[off + 4 + i] = p1[i]; }
        }
        __syncthreads();
        if (kp == 0) {
#pragma unroll
            for (int w = 0; w < 7; ++w) {
                const int off = ((cp * 7 + w) * 64 + lane) * 9;
#pragma unroll
                for (int i = 0; i < 4; ++i) { p0[i] += red[off + i]; p1[i] += red[off + 4 + i]; }
            }
#pragma unroll
            for (int t = 0; t < 2; ++t) {
                const int o = cp * 32 + t * 16 + mm;
                const float bi = bias[o];
                floatx4& P = t ? p1 : p0;
#pragma unroll
                for (int r = 0; r < 4; ++r) {
                    const int n = node0 + qq * 4 + r;
                    float v = P[r] + bi;
                    if (RELU) {
                        v = fmaxf(v, 0.f);
                        reinterpret_cast<__hip_bfloat16*>(outp)[(size_t)n * DOUT + o] =
                            __float2bfloat16(v);
                    } else {
                        reinterpret_cast<float*>(outp)[(size_t)n * DOUT + o] = v;
                    }
                }
            }
        }
    } else {
        if (kp > 0) {
            const int off = (((kp - 1)) * 64 + lane) * 5;
#pragma unroll
            for (int i = 0; i < 4; ++i) red[off + i] = p0[i];
        }
        __syncthreads();
        if (kp == 0) {
#pragma unroll
            for (int w = 0; w < 15; ++w) {
                const int off = (w * 64 + lane) * 5;
#pragma unroll
                for (int i = 0; i < 4; ++i) p0[i] += red[off + i];
            }
            if (mm < DOUT) {
                const float bi = bias[mm];
#pragma unroll
                for (int r = 0; r < 4; ++r) {
                    const int n = node0 + qq * 4 + r;
                    reinterpret_cast<float*>(outp)[(size_t)n * DOUT + mm] = p0[r] + bi;
                }
            }
        }
    }
}

// ---------------- log_softmax over C=8 ----------------
__global__ void k_lsm(const float* __restrict__ pre, float* __restrict__ out) {
    int n = blockIdx.x * 256 + threadIdx.x;
    if (n < NN) {
        float v[8];
        float mx = -1e30f;
#pragma unroll
        for (int c = 0; c < 8; ++c) { v[c] = pre[n * 8 + c]; mx = fmaxf(mx, v[c]); }
        float s = 0.f;
#pragma unroll
        for (int c = 0; c < 8; ++c) s += expf(v[c] - mx);
        float ls = logf(s);
#pragma unroll
        for (int c = 0; c < 8; ++c) out[n * 8 + c] = v[c] - mx - ls;
    }
}

// ---------------- launch ----------------
extern "C" void kernel_launch(void* const* d_in, const int* in_sizes, int n_in,
                              void* d_out, int out_size, void* d_ws, size_t ws_size,
                              hipStream_t stream) {
    const float* x     = (const float*)d_in[0];
    const int*   eidx  = (const int*)d_in[1];
    const int*   etype = (const int*)d_in[2];
    const float* bases0 = (const float*)d_in[3];
    const float* comp0  = (const float*)d_in[4];
    const float* root0  = (const float*)d_in[5];
    const float* bias0  = (const float*)d_in[6];
    const float* bases1 = (const float*)d_in[7];
    const float* comp1  = (const float*)d_in[8];
    const float* root1  = (const float*)d_in[9];
    const float* bias1  = (const float*)d_in[10];
    const float* bases2 = (const float*)d_in[11];
    const float* comp2  = (const float*)d_in[12];
    const float* root2  = (const float*)d_in[13];
    const float* bias2  = (const float*)d_in[14];
    const int* srcp = eidx;
    const int* dstp = eidx + EE;

    char* p = (char*)d_ws;
    auto carve = [&](size_t bytes) -> char* {
        char* r = p;
        p += (bytes + 255) & ~(size_t)255;
        return r;
    };
    int*  cnt    = (int*)carve((size_t)NN * RR * sizeof(int));   // 10 MB
    int*  dcount = (int*)carve((size_t)NN * sizeof(int));
    int*  cursor = (int*)carve((size_t)NN * sizeof(int));
    int*  doff   = (int*)carve((size_t)NN * sizeof(int));
    int*  bsum   = (int*)carve(256 * sizeof(int));
    int4* epack  = (int4*)carve((size_t)EE * sizeof(int4) + 512);  // +slack for clamped tail reads
    __hip_bfloat16* h0 = (__hip_bfloat16*)carve((size_t)NN * DIN * 2);
    __hip_bfloat16* h1 = (__hip_bfloat16*)carve((size_t)NN * DIN * 2);
    __hip_bfloat16* h2 = (__hip_bfloat16*)carve((size_t)NN * DIN * 2);
    float* pre = (float*)carve((size_t)NN * 8 * sizeof(float));
    short* wtA = (short*)carve((size_t)144 * KTOT * sizeof(short));  // 3 layers stacked
    short* cbA = (short*)carve((size_t)3 * RR * 32 * sizeof(short)); // bf16 comp tables

    // cnt, dcount, cursor adjacent -> one memset
    hipMemsetAsync(cnt, 0, (size_t)NN * (RR + 2) * sizeof(int) + 512, stream);

    const int EB = (EE + 255) / 256;   // 3907
    const int NB = (NN + 255) / 256;   // 196
    k_hist<<<EB, 256, 0, stream>>>(dstp, etype, cnt, dcount);
    k_scan1<<<NB, 256, 0, stream>>>(dcount, doff, bsum);
    k_scan2<<<1, 256, 0, stream>>>(bsum, NB);
    k_scan3<<<NB, 256, 0, stream>>>(doff, bsum);
    k_scatter<<<EB, 256, 0, stream>>>(srcp, dstp, etype, cnt, doff, cursor, epack);
    k_cast_x<<<(NN * DIN + 255) / 256, 256, 0, stream>>>(x, h0);
    k_prep_cb3<<<(3 * RR * 32 + 255) / 256, 256, 0, stream>>>(comp0, comp1, comp2, cbA);
    k_prep_w3<<<(144 * KTOT + 255) / 256, 256, 0, stream>>>(bases0, root0, bases1, root1,
                                                            bases2, root2, wtA);

    short* wt0 = wtA;
    short* wt1 = wtA + (size_t)64 * KTOT;
    short* wt2 = wtA + (size_t)128 * KTOT;
    short* cb0 = cbA;
    short* cb1 = cbA + RR * 32;
    short* cb2 = cbA + 2 * RR * 32;

    const int NF = NN / NBW;   // 3125 (exact)
    k_fused<64, true ><<<NF, 1024, 0, stream>>>(h0, epack, doff, dcount, cb0, wt0, bias0, (void*)h1);
    k_fused<64, true ><<<NF, 1024, 0, stream>>>(h1, epack, doff, dcount, cb1, wt1, bias1, (void*)h2);
    k_fused<8,  false><<<NF, 1024, 0, stream>>>(h2, epack, doff, dcount, cb2, wt2, bias2, (void*)pre);
    k_lsm<<<NB, 256, 0, stream>>>(pre, (float*)d_out);
}